// Round 1
// baseline (1611.731 us; speedup 1.0000x reference)
//
#include <hip/hip_runtime.h>
#include <math.h>

#define T_SEQ 1024
#define NH 16
#define HD 64

// monotone float -> uint key: a<b (float) <=> fkey(a)<fkey(b) (uint)
__device__ __forceinline__ unsigned fkey(float x) {
  unsigned u = __float_as_uint(x);
  return (u & 0x80000000u) ? ~u : (u | 0x80000000u);
}

// ---------------- K1: QKV = X[4096,1024] @ W[1024,3072] + b, scatter to Q/K/V [B,nH,T,hd] ----------------
__global__ __launch_bounds__(256) void k_qkv(
    const float* __restrict__ X, const float* __restrict__ W, const float* __restrict__ bias,
    float* __restrict__ Q, float* __restrict__ Kb, float* __restrict__ V) {
  const int K = 1024, N = 3072;
  __shared__ float As[16][132];
  __shared__ float Bs[16][132];
  const int tid = threadIdx.x;
  const int m0 = blockIdx.y * 128;
  const int n0 = blockIdx.x * 128;
  const int ty = tid >> 4, tx = tid & 15;
  float acc[8][8];
#pragma unroll
  for (int i = 0; i < 8; ++i)
#pragma unroll
    for (int j = 0; j < 8; ++j) acc[i][j] = 0.f;

  const int arow = tid >> 2, acol = (tid & 3) << 2;
  const int brow = tid >> 5, bcol = (tid & 31) << 2;

  for (int k0 = 0; k0 < K; k0 += 16) {
#pragma unroll
    for (int r = 0; r < 2; ++r) {
      const int row = arow + (r << 6);
      const float4 a = *(const float4*)(X + (size_t)(m0 + row) * K + (k0 + acol));
      As[acol + 0][row] = a.x; As[acol + 1][row] = a.y;
      As[acol + 2][row] = a.z; As[acol + 3][row] = a.w;
    }
#pragma unroll
    for (int r = 0; r < 2; ++r) {
      const int row = brow + (r << 3);
      *(float4*)&Bs[row][bcol] = *(const float4*)(W + (size_t)(k0 + row) * N + (n0 + bcol));
    }
    __syncthreads();
#pragma unroll
    for (int kk = 0; kk < 16; ++kk) {
      const float4 a0 = *(const float4*)&As[kk][ty << 3];
      const float4 a1 = *(const float4*)&As[kk][(ty << 3) + 4];
      const float4 b0 = *(const float4*)&Bs[kk][tx << 3];
      const float4 b1 = *(const float4*)&Bs[kk][(tx << 3) + 4];
      const float av[8] = {a0.x, a0.y, a0.z, a0.w, a1.x, a1.y, a1.z, a1.w};
      const float bv[8] = {b0.x, b0.y, b0.z, b0.w, b1.x, b1.y, b1.z, b1.w};
#pragma unroll
      for (int i = 0; i < 8; ++i)
#pragma unroll
        for (int j = 0; j < 8; ++j) acc[i][j] = fmaf(av[i], bv[j], acc[i][j]);
    }
    __syncthreads();
  }
#pragma unroll
  for (int i = 0; i < 8; ++i) {
    const int m = m0 + (ty << 3) + i;
    const int b = m >> 10, t = m & 1023;
#pragma unroll
    for (int j = 0; j < 8; ++j) {
      const int n = n0 + (tx << 3) + j;
      const float v = acc[i][j] + bias[n];
      const int which = n >> 10;
      const int c = n & 1023;
      const size_t dst = ((size_t)((b * NH + (c >> 6)) * T_SEQ + t) << 6) + (c & 63);
      if (which == 0) Q[dst] = v;
      else if (which == 1) Kb[dst] = v;
      else V[dst] = v;
    }
  }
}

// ---------------- K2: ATT[z] = Q[z] @ K[z]^T * 0.125 (z = b*16+h) ----------------
__global__ __launch_bounds__(256) void k_att(
    const float* __restrict__ Q, const float* __restrict__ Kb, float* __restrict__ ATT) {
  __shared__ float As[16][132];
  __shared__ float Bs[16][132];
  const int tid = threadIdx.x;
  const int z = blockIdx.z;
  const float* Qz = Q + (size_t)z * T_SEQ * HD;
  const float* Kz = Kb + (size_t)z * T_SEQ * HD;
  float* Az = ATT + (size_t)z * T_SEQ * T_SEQ;
  const int m0 = blockIdx.y * 128, n0 = blockIdx.x * 128;
  const int ty = tid >> 4, tx = tid & 15;
  float acc[8][8];
#pragma unroll
  for (int i = 0; i < 8; ++i)
#pragma unroll
    for (int j = 0; j < 8; ++j) acc[i][j] = 0.f;

  const int lrow = tid >> 2, lcol = (tid & 3) << 2;

  for (int k0 = 0; k0 < HD; k0 += 16) {
#pragma unroll
    for (int r = 0; r < 2; ++r) {
      const int row = lrow + (r << 6);
      const float4 a = *(const float4*)(Qz + (size_t)(m0 + row) * HD + (k0 + lcol));
      As[lcol + 0][row] = a.x; As[lcol + 1][row] = a.y;
      As[lcol + 2][row] = a.z; As[lcol + 3][row] = a.w;
      const float4 b = *(const float4*)(Kz + (size_t)(n0 + row) * HD + (k0 + lcol));
      Bs[lcol + 0][row] = b.x; Bs[lcol + 1][row] = b.y;
      Bs[lcol + 2][row] = b.z; Bs[lcol + 3][row] = b.w;
    }
    __syncthreads();
#pragma unroll
    for (int kk = 0; kk < 16; ++kk) {
      const float4 a0 = *(const float4*)&As[kk][ty << 3];
      const float4 a1 = *(const float4*)&As[kk][(ty << 3) + 4];
      const float4 b0 = *(const float4*)&Bs[kk][tx << 3];
      const float4 b1 = *(const float4*)&Bs[kk][(tx << 3) + 4];
      const float av[8] = {a0.x, a0.y, a0.z, a0.w, a1.x, a1.y, a1.z, a1.w};
      const float bv[8] = {b0.x, b0.y, b0.z, b0.w, b1.x, b1.y, b1.z, b1.w};
#pragma unroll
      for (int i = 0; i < 8; ++i)
#pragma unroll
        for (int j = 0; j < 8; ++j) acc[i][j] = fmaf(av[i], bv[j], acc[i][j]);
    }
    __syncthreads();
  }
#pragma unroll
  for (int i = 0; i < 8; ++i)
#pragma unroll
    for (int j = 0; j < 8; ++j)
      Az[(size_t)(m0 + (ty << 3) + i) * T_SEQ + (n0 + (tx << 3) + j)] = acc[i][j] * 0.125f;
}

// ---------------- K3: per-row gumbel top-k select + double softmax; P overwrites ATT ----------------
__global__ __launch_bounds__(256) void k_select(
    const float* __restrict__ ATT, float* __restrict__ P,
    const float* __restrict__ NOISE,
    const float* __restrict__ SR, const float* __restrict__ GT) {
  __shared__ unsigned hist[256];
  __shared__ unsigned redu[256];
  __shared__ float redf[256];
  __shared__ unsigned s_beta;

  const int row = blockIdx.x;          // (b*16+h)*1024 + t
  const int t = row & 1023;
  const int h = (row >> 10) & 15;
  const int tid = threadIdx.x;

  const float ratio = 1.f / (1.f + expf(-SR[h]));
  const float temp = log1pf(expf(GT[h])) + 0.1f;
  const int kf = (int)floorf((float)(t + 1) * ratio);
  const unsigned k = (unsigned)(kf < 1 ? 1 : kf);

  // each thread owns columns [4*tid, 4*tid+3]
  const float4 a4 = ((const float4*)(ATT + (size_t)row * 1024))[tid];
  const float4 u4 = ((const float4*)(NOISE + (size_t)row * 1024))[tid];
  const float av[4] = {a4.x, a4.y, a4.z, a4.w};
  const float uv[4] = {u4.x, u4.y, u4.z, u4.w};
  float gv[4];
  unsigned keyv[4];
#pragma unroll
  for (int j = 0; j < 4; ++j) {
    const int idx = (tid << 2) + j;
    const float g = -logf(-logf(uv[j] + 1e-8f) + 1e-8f);
    gv[j] = (idx <= t) ? (av[j] + g) / temp : -INFINITY;
    keyv[j] = fkey(gv[j]);
  }

  // radix-select the k-th largest key (exact bits), 4 passes of 8 bits
  unsigned want = 0u, mask = 0u, rem = k;
  for (int pass = 3; pass >= 0; --pass) {
    const int shift = pass << 3;
    hist[tid] = 0u;
    __syncthreads();
#pragma unroll
    for (int j = 0; j < 4; ++j)
      if ((keyv[j] & mask) == want) atomicAdd(&hist[(keyv[j] >> shift) & 255u], 1u);
    __syncthreads();
    redu[tid] = hist[tid];
    __syncthreads();
    for (int off = 1; off < 256; off <<= 1) {    // suffix sum (Hillis-Steele)
      const unsigned add = (tid + off < 256) ? redu[tid + off] : 0u;
      __syncthreads();
      redu[tid] += add;
      __syncthreads();
    }
    const unsigned mine = redu[tid];
    const unsigned nxt = (tid < 255) ? redu[tid + 1] : 0u;
    if (mine >= rem && nxt < rem) s_beta = (unsigned)tid;   // unique
    __syncthreads();
    const unsigned beta = s_beta;
    rem -= (beta < 255u) ? redu[beta + 1] : 0u;
    want |= beta << shift;
    mask |= 255u << shift;
    __syncthreads();
  }
  const unsigned tau = want;    // exact key of k-th largest
  const unsigned need = rem;    // how many tau-ties to take (lowest index first)

  // row max of gl
  float lm = fmaxf(fmaxf(gv[0], gv[1]), fmaxf(gv[2], gv[3]));
  redf[tid] = lm;
  __syncthreads();
  for (int off = 128; off > 0; off >>= 1) {
    if (tid < off) redf[tid] = fmaxf(redf[tid], redf[tid + off]);
    __syncthreads();
  }
  const float m = redf[0];
  __syncthreads();

  // stable tie-break: exclusive prefix of tie count in index order
  unsigned tloc = 0;
  bool tie[4];
#pragma unroll
  for (int j = 0; j < 4; ++j) { tie[j] = (keyv[j] == tau); tloc += tie[j] ? 1u : 0u; }
  redu[tid] = tloc;
  __syncthreads();
  for (int off = 1; off < 256; off <<= 1) {      // inclusive prefix sum
    const unsigned add = (tid >= off) ? redu[tid - off] : 0u;
    __syncthreads();
    redu[tid] += add;
    __syncthreads();
  }
  unsigned run = (tid > 0) ? redu[tid - 1] : 0u;

  bool sel[4];
  float ex[4];
  float psum = 0.f;
#pragma unroll
  for (int j = 0; j < 4; ++j) {
    bool s = (keyv[j] > tau);
    if (tie[j]) { s = (run < need); run += 1u; }
    sel[j] = s;
    ex[j] = s ? expf(gv[j] - m) : 0.f;
    psum += ex[j];
  }
  redf[tid] = psum;
  __syncthreads();
  for (int off = 128; off > 0; off >>= 1) {
    if (tid < off) redf[tid] += redf[tid + off];
    __syncthreads();
  }
  const float S = redf[0];
  __syncthreads();

  // sparse = selected ? att * sv : 0
  float sp[4];
#pragma unroll
  for (int j = 0; j < 4; ++j) sp[j] = sel[j] ? av[j] * (ex[j] / S) : 0.f;

  // final softmax over the FULL row (zeros at unselected/non-causal)
  float lM = fmaxf(fmaxf(sp[0], sp[1]), fmaxf(sp[2], sp[3]));
  lM = fmaxf(lM, 0.f);
  redf[tid] = lM;
  __syncthreads();
  for (int off = 128; off > 0; off >>= 1) {
    if (tid < off) redf[tid] = fmaxf(redf[tid], redf[tid + off]);
    __syncthreads();
  }
  const float M = redf[0];
  __syncthreads();

  float e[4];
  float lz = 0.f;
#pragma unroll
  for (int j = 0; j < 4; ++j) { e[j] = expf(sp[j] - M); lz += e[j]; }
  redf[tid] = lz;
  __syncthreads();
  for (int off = 128; off > 0; off >>= 1) {
    if (tid < off) redf[tid] += redf[tid + off];
    __syncthreads();
  }
  const float Z = redf[0];
  const float invZ = 1.f / Z;
  ((float4*)(P + (size_t)row * 1024))[tid] =
      make_float4(e[0] * invZ, e[1] * invZ, e[2] * invZ, e[3] * invZ);
}

// ---------------- K4: Y[b,t,h*64+d] = sum_k P[z,t,k] * V[z,k,d] ----------------
__global__ __launch_bounds__(256) void k_pv(
    const float* __restrict__ P, const float* __restrict__ V, float* __restrict__ Y) {
  __shared__ float As[32][68];
  __shared__ float Bs[32][68];
  const int tid = threadIdx.x;
  const int z = blockIdx.z;
  const int b = z >> 4, h = z & 15;
  const float* Pz = P + (size_t)z * T_SEQ * T_SEQ;
  const float* Vz = V + (size_t)z * T_SEQ * HD;
  const int m0 = blockIdx.x * 64;
  const int ty = tid >> 4, tx = tid & 15;
  float acc[4][4];
#pragma unroll
  for (int i = 0; i < 4; ++i)
#pragma unroll
    for (int j = 0; j < 4; ++j) acc[i][j] = 0.f;

  const int prow = tid >> 3, pcol = (tid & 7) << 2;
  const int vrow = tid >> 4, vcol = (tid & 15) << 2;

  for (int k0 = 0; k0 < T_SEQ; k0 += 32) {
#pragma unroll
    for (int r = 0; r < 2; ++r) {
      const int row = prow + (r << 5);
      const float4 a = *(const float4*)(Pz + (size_t)(m0 + row) * T_SEQ + (k0 + pcol));
      As[pcol + 0][row] = a.x; As[pcol + 1][row] = a.y;
      As[pcol + 2][row] = a.z; As[pcol + 3][row] = a.w;
      const int rowb = vrow + (r << 4);
      *(float4*)&Bs[rowb][vcol] = *(const float4*)(Vz + (size_t)(k0 + rowb) * HD + vcol);
    }
    __syncthreads();
#pragma unroll
    for (int kk = 0; kk < 32; ++kk) {
      const float4 a = *(const float4*)&As[kk][ty << 2];
      const float4 bv = *(const float4*)&Bs[kk][tx << 2];
      const float avv[4] = {a.x, a.y, a.z, a.w};
      const float bb[4] = {bv.x, bv.y, bv.z, bv.w};
#pragma unroll
      for (int i = 0; i < 4; ++i)
#pragma unroll
        for (int j = 0; j < 4; ++j) acc[i][j] = fmaf(avv[i], bb[j], acc[i][j]);
    }
    __syncthreads();
  }
#pragma unroll
  for (int i = 0; i < 4; ++i) {
    const int trow = m0 + (ty << 2) + i;
#pragma unroll
    for (int j = 0; j < 4; ++j)
      Y[((size_t)(b * T_SEQ + trow) << 10) + (h << 6) + (tx << 2) + j] = acc[i][j];
  }
}

// ---------------- K5: OUT = Y[4096,1024] @ W_proj[1024,1024] + b_proj ----------------
__global__ __launch_bounds__(256) void k_proj(
    const float* __restrict__ Yin, const float* __restrict__ W, const float* __restrict__ bias,
    float* __restrict__ OUT) {
  const int K = 1024, N = 1024;
  __shared__ float As[16][132];
  __shared__ float Bs[16][132];
  const int tid = threadIdx.x;
  const int m0 = blockIdx.y * 128;
  const int n0 = blockIdx.x * 128;
  const int ty = tid >> 4, tx = tid & 15;
  float acc[8][8];
#pragma unroll
  for (int i = 0; i < 8; ++i)
#pragma unroll
    for (int j = 0; j < 8; ++j) acc[i][j] = 0.f;

  const int arow = tid >> 2, acol = (tid & 3) << 2;
  const int brow = tid >> 5, bcol = (tid & 31) << 2;

  for (int k0 = 0; k0 < K; k0 += 16) {
#pragma unroll
    for (int r = 0; r < 2; ++r) {
      const int row = arow + (r << 6);
      const float4 a = *(const float4*)(Yin + (size_t)(m0 + row) * K + (k0 + acol));
      As[acol + 0][row] = a.x; As[acol + 1][row] = a.y;
      As[acol + 2][row] = a.z; As[acol + 3][row] = a.w;
    }
#pragma unroll
    for (int r = 0; r < 2; ++r) {
      const int row = brow + (r << 3);
      *(float4*)&Bs[row][bcol] = *(const float4*)(W + (size_t)(k0 + row) * N + (n0 + bcol));
    }
    __syncthreads();
#pragma unroll
    for (int kk = 0; kk < 16; ++kk) {
      const float4 a0 = *(const float4*)&As[kk][ty << 3];
      const float4 a1 = *(const float4*)&As[kk][(ty << 3) + 4];
      const float4 b0 = *(const float4*)&Bs[kk][tx << 3];
      const float4 b1 = *(const float4*)&Bs[kk][(tx << 3) + 4];
      const float av[8] = {a0.x, a0.y, a0.z, a0.w, a1.x, a1.y, a1.z, a1.w};
      const float bv[8] = {b0.x, b0.y, b0.z, b0.w, b1.x, b1.y, b1.z, b1.w};
#pragma unroll
      for (int i = 0; i < 8; ++i)
#pragma unroll
        for (int j = 0; j < 8; ++j) acc[i][j] = fmaf(av[i], bv[j], acc[i][j]);
    }
    __syncthreads();
  }
#pragma unroll
  for (int i = 0; i < 8; ++i) {
    const int m = m0 + (ty << 3) + i;
#pragma unroll
    for (int j = 0; j < 8; ++j) {
      const int n = n0 + (tx << 3) + j;
      OUT[(size_t)m * N + n] = acc[i][j] + bias[n];
    }
  }
}

extern "C" void kernel_launch(void* const* d_in, const int* in_sizes, int n_in,
                              void* d_out, int out_size, void* d_ws, size_t ws_size,
                              hipStream_t stream) {
  const float* x      = (const float*)d_in[0];
  const float* W_attn = (const float*)d_in[1];
  const float* b_attn = (const float*)d_in[2];
  const float* W_proj = (const float*)d_in[3];
  const float* b_proj = (const float*)d_in[4];
  const float* sr     = (const float*)d_in[5];
  const float* gt     = (const float*)d_in[6];
  const float* noise  = (const float*)d_in[7];

  float* ws  = (float*)d_ws;
  float* Q   = ws;               // 4,194,304 floats
  float* K   = ws + 4194304;
  float* V   = ws + 8388608;
  float* ATT = ws + 12582912;    // 67,108,864 floats (reused as P in-place)
  float* Y   = ws + 79691776;    // 4,194,304 floats
  float* OUT = (float*)d_out;

  k_qkv  <<<dim3(24, 32),   256, 0, stream>>>(x, W_attn, b_attn, Q, K, V);
  k_att  <<<dim3(8, 8, 64), 256, 0, stream>>>(Q, K, ATT);
  k_select<<<dim3(65536),   256, 0, stream>>>(ATT, ATT, noise, sr, gt);
  k_pv   <<<dim3(16, 1, 64),256, 0, stream>>>(ATT, V, Y);
  k_proj <<<dim3(8, 32),    256, 0, stream>>>(Y, W_proj, b_proj, OUT);
}

// Round 2
// 1293.709 us; speedup vs baseline: 1.2458x; 1.2458x over previous
//
#include <hip/hip_runtime.h>
#include <math.h>

#define T_SEQ 1024
#define NH 16
#define HD 64

// monotone float -> uint key: a<b (float) <=> fkey(a)<fkey(b) (uint)
__device__ __forceinline__ unsigned fkey(float x) {
  unsigned u = __float_as_uint(x);
  return (u & 0x80000000u) ? ~u : (u | 0x80000000u);
}

__device__ __forceinline__ float wredmax(float v) {
#pragma unroll
  for (int m = 1; m < 64; m <<= 1) v = fmaxf(v, __shfl_xor(v, m));
  return v;
}
__device__ __forceinline__ float wredsum(float v) {
#pragma unroll
  for (int m = 1; m < 64; m <<= 1) v += __shfl_xor(v, m);
  return v;
}

// ---------------- K1: QKV = X[4096,1024] @ W[1024,3072] + b, scatter to Q/K/V [B,nH,T,hd] ----------------
__global__ __launch_bounds__(256) void k_qkv(
    const float* __restrict__ X, const float* __restrict__ W, const float* __restrict__ bias,
    float* __restrict__ Q, float* __restrict__ Kb, float* __restrict__ V) {
  const int K = 1024, N = 3072;
  __shared__ float As[16][132];
  __shared__ float Bs[16][132];
  const int tid = threadIdx.x;
  const int m0 = blockIdx.y * 128;
  const int n0 = blockIdx.x * 128;
  const int ty = tid >> 4, tx = tid & 15;
  float acc[8][8];
#pragma unroll
  for (int i = 0; i < 8; ++i)
#pragma unroll
    for (int j = 0; j < 8; ++j) acc[i][j] = 0.f;

  const int arow = tid >> 2, acol = (tid & 3) << 2;
  const int brow = tid >> 5, bcol = (tid & 31) << 2;

  for (int k0 = 0; k0 < K; k0 += 16) {
#pragma unroll
    for (int r = 0; r < 2; ++r) {
      const int row = arow + (r << 6);
      const float4 a = *(const float4*)(X + (size_t)(m0 + row) * K + (k0 + acol));
      As[acol + 0][row] = a.x; As[acol + 1][row] = a.y;
      As[acol + 2][row] = a.z; As[acol + 3][row] = a.w;
    }
#pragma unroll
    for (int r = 0; r < 2; ++r) {
      const int row = brow + (r << 3);
      *(float4*)&Bs[row][bcol] = *(const float4*)(W + (size_t)(k0 + row) * N + (n0 + bcol));
    }
    __syncthreads();
#pragma unroll
    for (int kk = 0; kk < 16; ++kk) {
      const float4 a0 = *(const float4*)&As[kk][ty << 3];
      const float4 a1 = *(const float4*)&As[kk][(ty << 3) + 4];
      const float4 b0 = *(const float4*)&Bs[kk][tx << 3];
      const float4 b1 = *(const float4*)&Bs[kk][(tx << 3) + 4];
      const float av[8] = {a0.x, a0.y, a0.z, a0.w, a1.x, a1.y, a1.z, a1.w};
      const float bv[8] = {b0.x, b0.y, b0.z, b0.w, b1.x, b1.y, b1.z, b1.w};
#pragma unroll
      for (int i = 0; i < 8; ++i)
#pragma unroll
        for (int j = 0; j < 8; ++j) acc[i][j] = fmaf(av[i], bv[j], acc[i][j]);
    }
    __syncthreads();
  }
#pragma unroll
  for (int i = 0; i < 8; ++i) {
    const int m = m0 + (ty << 3) + i;
    const int b = m >> 10, t = m & 1023;
#pragma unroll
    for (int j = 0; j < 8; ++j) {
      const int n = n0 + (tx << 3) + j;
      const float v = acc[i][j] + bias[n];
      const int which = n >> 10;
      const int c = n & 1023;
      const size_t dst = ((size_t)((b * NH + (c >> 6)) * T_SEQ + t) << 6) + (c & 63);
      if (which == 0) Q[dst] = v;
      else if (which == 1) Kb[dst] = v;
      else V[dst] = v;
    }
  }
}

// ---------------- K2: ATT[z] = Q[z] @ K[z]^T * 0.125 (z = b*16+h) ----------------
__global__ __launch_bounds__(256) void k_att(
    const float* __restrict__ Q, const float* __restrict__ Kb, float* __restrict__ ATT) {
  __shared__ float As[16][132];
  __shared__ float Bs[16][132];
  const int tid = threadIdx.x;
  const int z = blockIdx.z;
  const float* Qz = Q + (size_t)z * T_SEQ * HD;
  const float* Kz = Kb + (size_t)z * T_SEQ * HD;
  float* Az = ATT + (size_t)z * T_SEQ * T_SEQ;
  const int m0 = blockIdx.y * 128, n0 = blockIdx.x * 128;
  const int ty = tid >> 4, tx = tid & 15;
  float acc[8][8];
#pragma unroll
  for (int i = 0; i < 8; ++i)
#pragma unroll
    for (int j = 0; j < 8; ++j) acc[i][j] = 0.f;

  const int lrow = tid >> 2, lcol = (tid & 3) << 2;

  for (int k0 = 0; k0 < HD; k0 += 16) {
#pragma unroll
    for (int r = 0; r < 2; ++r) {
      const int row = lrow + (r << 6);
      const float4 a = *(const float4*)(Qz + (size_t)(m0 + row) * HD + (k0 + lcol));
      As[lcol + 0][row] = a.x; As[lcol + 1][row] = a.y;
      As[lcol + 2][row] = a.z; As[lcol + 3][row] = a.w;
      const float4 b = *(const float4*)(Kz + (size_t)(n0 + row) * HD + (k0 + lcol));
      Bs[lcol + 0][row] = b.x; Bs[lcol + 1][row] = b.y;
      Bs[lcol + 2][row] = b.z; Bs[lcol + 3][row] = b.w;
    }
    __syncthreads();
#pragma unroll
    for (int kk = 0; kk < 16; ++kk) {
      const float4 a0 = *(const float4*)&As[kk][ty << 3];
      const float4 a1 = *(const float4*)&As[kk][(ty << 3) + 4];
      const float4 b0 = *(const float4*)&Bs[kk][tx << 3];
      const float4 b1 = *(const float4*)&Bs[kk][(tx << 3) + 4];
      const float av[8] = {a0.x, a0.y, a0.z, a0.w, a1.x, a1.y, a1.z, a1.w};
      const float bv[8] = {b0.x, b0.y, b0.z, b0.w, b1.x, b1.y, b1.z, b1.w};
#pragma unroll
      for (int i = 0; i < 8; ++i)
#pragma unroll
        for (int j = 0; j < 8; ++j) acc[i][j] = fmaf(av[i], bv[j], acc[i][j]);
    }
    __syncthreads();
  }
#pragma unroll
  for (int i = 0; i < 8; ++i)
#pragma unroll
    for (int j = 0; j < 8; ++j)
      Az[(size_t)(m0 + (ty << 3) + i) * T_SEQ + (n0 + (tx << 3) + j)] = acc[i][j] * 0.125f;
}

// ---------------- K3: per-row gumbel top-k select + double softmax ----------------
// One wave per row. Zero LDS, zero __syncthreads. Each lane owns 16 columns:
// col(s,j) = s*256 + lane*4 + j, s=0..3, j=0..3 (float4-coalesced).
__global__ __launch_bounds__(256) void k_select(
    const float* __restrict__ ATT, float* __restrict__ P,
    const float* __restrict__ NOISE,
    const float* __restrict__ SR, const float* __restrict__ GT) {
  const int tid = threadIdx.x;
  const int lane = tid & 63;
  const int row = (blockIdx.x << 2) | (tid >> 6);
  const int t = row & 1023;
  const int h = (row >> 10) & 15;

  const float ratio = 1.f / (1.f + __expf(-SR[h]));
  const float temp = log1pf(__expf(GT[h])) + 0.1f;
  const float invtemp = 1.f / temp;
  const int kf = (int)floorf((float)(t + 1) * ratio);
  const unsigned k = (unsigned)(kf < 1 ? 1 : kf);

  const float4* arow = (const float4*)(ATT + ((size_t)row << 10));
  const float4* urow = (const float4*)(NOISE + ((size_t)row << 10));

  float av[16], gv[16];
  unsigned key[16];
#pragma unroll
  for (int s = 0; s < 4; ++s) {
    const float4 a4 = arow[(s << 6) + lane];
    const float4 u4 = urow[(s << 6) + lane];
    const float aa[4] = {a4.x, a4.y, a4.z, a4.w};
    const float uu[4] = {u4.x, u4.y, u4.z, u4.w};
#pragma unroll
    for (int j = 0; j < 4; ++j) {
      const int e = (s << 2) + j;
      const int col = (s << 8) + (lane << 2) + j;
      const float g = -__logf(-__logf(uu[j] + 1e-8f) + 1e-8f);
      av[e] = aa[j];
      gv[e] = (col <= t) ? (aa[j] + g) * invtemp : -INFINITY;
      key[e] = fkey(gv[e]);
    }
  }

  // bitwise binary search for tau = k-th largest key (exact).
  // invariant: #{key >= th} >= k. count via wave ballot (SALU popcount).
  unsigned th = 0u;
#pragma unroll
  for (int b = 31; b >= 0; --b) {
    const unsigned cand = th | (1u << b);
    unsigned c = 0;
#pragma unroll
    for (int e = 0; e < 16; ++e)
      c += (unsigned)__popcll(__ballot(key[e] >= cand));
    if (c >= k) th = cand;
  }
  const unsigned tau = th;

  // how many tau-ties to take, index order (stable argsort semantics)
  unsigned cnt_gt = 0;
#pragma unroll
  for (int e = 0; e < 16; ++e)
    cnt_gt += (unsigned)__popcll(__ballot(key[e] > tau));
  const unsigned need = k - cnt_gt;

  const unsigned long long below = ((unsigned long long)1 << lane) - 1ull;
  unsigned rank[16];
  unsigned base = 0;
#pragma unroll
  for (int s = 0; s < 4; ++s) {
    unsigned lanecnt = 0, tot = 0, own = 0;
    unsigned long long B[4];
#pragma unroll
    for (int j = 0; j < 4; ++j) {
      B[j] = __ballot(key[(s << 2) + j] == tau);
      lanecnt += (unsigned)__popcll(B[j] & below);
      tot += (unsigned)__popcll(B[j]);
    }
#pragma unroll
    for (int j = 0; j < 4; ++j) {
      rank[(s << 2) + j] = base + lanecnt + own;
      own += (key[(s << 2) + j] == tau) ? 1u : 0u;
    }
    base += tot;
  }

  bool sel[16];
#pragma unroll
  for (int e = 0; e < 16; ++e)
    sel[e] = (key[e] > tau) | ((key[e] == tau) & (rank[e] < need));

  // softmax #1 over selected gl (row max over all gl == max over selected,
  // since the argmax is always selected)
  float lm = -INFINITY;
#pragma unroll
  for (int e = 0; e < 16; ++e) lm = fmaxf(lm, gv[e]);
  const float m = wredmax(lm);

  float ex[16];
  float ps = 0.f;
#pragma unroll
  for (int e = 0; e < 16; ++e) {
    ex[e] = sel[e] ? __expf(gv[e] - m) : 0.f;
    ps += ex[e];
  }
  const float S = wredsum(ps);
  const float invS = 1.f / S;

  // sparse = selected ? att * sv : 0
  float sp[16];
#pragma unroll
  for (int e = 0; e < 16; ++e) sp[e] = sel[e] ? av[e] * ex[e] * invS : 0.f;

  // final softmax over the FULL row (zeros at unselected/non-causal)
  float lM = 0.f;  // zeros are present in every row
#pragma unroll
  for (int e = 0; e < 16; ++e) lM = fmaxf(lM, sp[e]);
  const float M = wredmax(lM);

  float pe[16];
  float lz = 0.f;
#pragma unroll
  for (int e = 0; e < 16; ++e) { pe[e] = __expf(sp[e] - M); lz += pe[e]; }
  const float Z = wredsum(lz);
  const float invZ = 1.f / Z;

  float4* prow = (float4*)(P + ((size_t)row << 10));
#pragma unroll
  for (int s = 0; s < 4; ++s)
    prow[(s << 6) + lane] = make_float4(pe[(s << 2) + 0] * invZ, pe[(s << 2) + 1] * invZ,
                                        pe[(s << 2) + 2] * invZ, pe[(s << 2) + 3] * invZ);
}

// ---------------- K4: Y[b,t,h*64+d] = sum_k P[z,t,k] * V[z,k,d] ----------------
__global__ __launch_bounds__(256) void k_pv(
    const float* __restrict__ P, const float* __restrict__ V, float* __restrict__ Y) {
  __shared__ float As[32][68];
  __shared__ float Bs[32][68];
  const int tid = threadIdx.x;
  const int z = blockIdx.z;
  const int b = z >> 4, h = z & 15;
  const float* Pz = P + (size_t)z * T_SEQ * T_SEQ;
  const float* Vz = V + (size_t)z * T_SEQ * HD;
  const int m0 = blockIdx.x * 64;
  const int ty = tid >> 4, tx = tid & 15;
  float acc[4][4];
#pragma unroll
  for (int i = 0; i < 4; ++i)
#pragma unroll
    for (int j = 0; j < 4; ++j) acc[i][j] = 0.f;

  const int prow = tid >> 3, pcol = (tid & 7) << 2;
  const int vrow = tid >> 4, vcol = (tid & 15) << 2;

  for (int k0 = 0; k0 < T_SEQ; k0 += 32) {
#pragma unroll
    for (int r = 0; r < 2; ++r) {
      const int row = prow + (r << 5);
      const float4 a = *(const float4*)(Pz + (size_t)(m0 + row) * T_SEQ + (k0 + pcol));
      As[pcol + 0][row] = a.x; As[pcol + 1][row] = a.y;
      As[pcol + 2][row] = a.z; As[pcol + 3][row] = a.w;
      const int rowb = vrow + (r << 4);
      *(float4*)&Bs[rowb][vcol] = *(const float4*)(Vz + (size_t)(k0 + rowb) * HD + vcol);
    }
    __syncthreads();
#pragma unroll
    for (int kk = 0; kk < 32; ++kk) {
      const float4 a = *(const float4*)&As[kk][ty << 2];
      const float4 bv = *(const float4*)&Bs[kk][tx << 2];
      const float avv[4] = {a.x, a.y, a.z, a.w};
      const float bb[4] = {bv.x, bv.y, bv.z, bv.w};
#pragma unroll
      for (int i = 0; i < 4; ++i)
#pragma unroll
        for (int j = 0; j < 4; ++j) acc[i][j] = fmaf(avv[i], bb[j], acc[i][j]);
    }
    __syncthreads();
  }
#pragma unroll
  for (int i = 0; i < 4; ++i) {
    const int trow = m0 + (ty << 2) + i;
#pragma unroll
    for (int j = 0; j < 4; ++j)
      Y[((size_t)(b * T_SEQ + trow) << 10) + (h << 6) + (tx << 2) + j] = acc[i][j];
  }
}

// ---------------- K5: OUT = Y[4096,1024] @ W_proj[1024,1024] + b_proj ----------------
__global__ __launch_bounds__(256) void k_proj(
    const float* __restrict__ Yin, const float* __restrict__ W, const float* __restrict__ bias,
    float* __restrict__ OUT) {
  const int K = 1024, N = 1024;
  __shared__ float As[16][132];
  __shared__ float Bs[16][132];
  const int tid = threadIdx.x;
  const int m0 = blockIdx.y * 128;
  const int n0 = blockIdx.x * 128;
  const int ty = tid >> 4, tx = tid & 15;
  float acc[8][8];
#pragma unroll
  for (int i = 0; i < 8; ++i)
#pragma unroll
    for (int j = 0; j < 8; ++j) acc[i][j] = 0.f;

  const int arow = tid >> 2, acol = (tid & 3) << 2;
  const int brow = tid >> 5, bcol = (tid & 31) << 2;

  for (int k0 = 0; k0 < K; k0 += 16) {
#pragma unroll
    for (int r = 0; r < 2; ++r) {
      const int row = arow + (r << 6);
      const float4 a = *(const float4*)(Yin + (size_t)(m0 + row) * K + (k0 + acol));
      As[acol + 0][row] = a.x; As[acol + 1][row] = a.y;
      As[acol + 2][row] = a.z; As[acol + 3][row] = a.w;
    }
#pragma unroll
    for (int r = 0; r < 2; ++r) {
      const int row = brow + (r << 3);
      *(float4*)&Bs[row][bcol] = *(const float4*)(W + (size_t)(k0 + row) * N + (n0 + bcol));
    }
    __syncthreads();
#pragma unroll
    for (int kk = 0; kk < 16; ++kk) {
      const float4 a0 = *(const float4*)&As[kk][ty << 3];
      const float4 a1 = *(const float4*)&As[kk][(ty << 3) + 4];
      const float4 b0 = *(const float4*)&Bs[kk][tx << 3];
      const float4 b1 = *(const float4*)&Bs[kk][(tx << 3) + 4];
      const float av[8] = {a0.x, a0.y, a0.z, a0.w, a1.x, a1.y, a1.z, a1.w};
      const float bv[8] = {b0.x, b0.y, b0.z, b0.w, b1.x, b1.y, b1.z, b1.w};
#pragma unroll
      for (int i = 0; i < 8; ++i)
#pragma unroll
        for (int j = 0; j < 8; ++j) acc[i][j] = fmaf(av[i], bv[j], acc[i][j]);
    }
    __syncthreads();
  }
#pragma unroll
  for (int i = 0; i < 8; ++i) {
    const int m = m0 + (ty << 3) + i;
#pragma unroll
    for (int j = 0; j < 8; ++j) {
      const int n = n0 + (tx << 3) + j;
      OUT[(size_t)m * N + n] = acc[i][j] + bias[n];
    }
  }
}

extern "C" void kernel_launch(void* const* d_in, const int* in_sizes, int n_in,
                              void* d_out, int out_size, void* d_ws, size_t ws_size,
                              hipStream_t stream) {
  const float* x      = (const float*)d_in[0];
  const float* W_attn = (const float*)d_in[1];
  const float* b_attn = (const float*)d_in[2];
  const float* W_proj = (const float*)d_in[3];
  const float* b_proj = (const float*)d_in[4];
  const float* sr     = (const float*)d_in[5];
  const float* gt     = (const float*)d_in[6];
  const float* noise  = (const float*)d_in[7];

  float* ws  = (float*)d_ws;
  float* Q   = ws;               // 4,194,304 floats
  float* K   = ws + 4194304;
  float* V   = ws + 8388608;
  float* ATT = ws + 12582912;    // 67,108,864 floats (reused as P in-place)
  float* Y   = ws + 79691776;    // 4,194,304 floats
  float* OUT = (float*)d_out;

  k_qkv  <<<dim3(24, 32),   256, 0, stream>>>(x, W_attn, b_attn, Q, K, V);
  k_att  <<<dim3(8, 8, 64), 256, 0, stream>>>(Q, K, ATT);
  k_select<<<dim3(16384),   256, 0, stream>>>(ATT, ATT, noise, sr, gt);
  k_pv   <<<dim3(16, 1, 64),256, 0, stream>>>(ATT, V, Y);
  k_proj <<<dim3(8, 32),    256, 0, stream>>>(Y, W_proj, b_proj, OUT);
}

// Round 3
// 1046.964 us; speedup vs baseline: 1.5394x; 1.2357x over previous
//
#include <hip/hip_runtime.h>
#include <math.h>

#define T_SEQ 1024
#define NH 16
#define HD 64

typedef __attribute__((ext_vector_type(8))) short bf16x8;
typedef __attribute__((ext_vector_type(4))) float f32x4;

// monotone float -> uint key: a<b (float) <=> fkey(a)<fkey(b) (uint)
__device__ __forceinline__ unsigned fkey(float x) {
  unsigned u = __float_as_uint(x);
  return (u & 0x80000000u) ? ~u : (u | 0x80000000u);
}

__device__ __forceinline__ float wredmax(float v) {
#pragma unroll
  for (int m = 1; m < 64; m <<= 1) v = fmaxf(v, __shfl_xor(v, m));
  return v;
}
__device__ __forceinline__ float wredsum(float v) {
#pragma unroll
  for (int m = 1; m < 64; m <<= 1) v += __shfl_xor(v, m);
  return v;
}

// fp32 -> bf16 round-to-nearest-even (no NaN handling; inputs are finite)
__device__ __forceinline__ unsigned short f2bf(float f) {
  unsigned u = __float_as_uint(f);
  return (unsigned short)((u + 0x7fffu + ((u >> 16) & 1u)) >> 16);
}
__device__ __forceinline__ float bf2f(unsigned short h) {
  return __uint_as_float(((unsigned)h) << 16);
}

// async global->LDS, 16B per lane (dest = wave-uniform base + lane*16)
__device__ __forceinline__ void gl_lds16(const void* g, void* l) {
  __builtin_amdgcn_global_load_lds(
      (const __attribute__((address_space(1))) unsigned int*)g,
      (__attribute__((address_space(3))) unsigned int*)l,
      16, 0, 0);
}

// ---------------- P1: A3 = [hi(X) | hi(X) | lo(X)]  [4096][3072] bf16 ----------------
__global__ __launch_bounds__(256) void k_split_a(const float* __restrict__ X,
                                                 unsigned short* __restrict__ A3) {
  const int idx = blockIdx.x * 256 + threadIdx.x;   // float4 index
  const int m = idx >> 8;                           // 256 float4 per row of 1024
  const int c4 = idx & 255;
  const float4 x = ((const float4*)(X + ((size_t)m << 10)))[c4];
  const float xs[4] = {x.x, x.y, x.z, x.w};
  unsigned short hh[4], ll[4];
#pragma unroll
  for (int j = 0; j < 4; ++j) {
    hh[j] = f2bf(xs[j]);
    ll[j] = f2bf(xs[j] - bf2f(hh[j]));
  }
  const ushort4 h = make_ushort4(hh[0], hh[1], hh[2], hh[3]);
  const ushort4 l = make_ushort4(ll[0], ll[1], ll[2], ll[3]);
  ushort4* dst = (ushort4*)(A3 + (size_t)m * 3072);
  dst[c4] = h;
  dst[c4 + 256] = h;
  dst[c4 + 512] = l;
}

// ---------------- P2: B3t[n][k'] = [hi(W)^T | lo(W)^T | hi(W)^T]  [3072][3072] bf16 ----------------
__global__ __launch_bounds__(256) void k_split_bt(const float* __restrict__ W,
                                                  unsigned short* __restrict__ Bt) {
  __shared__ unsigned short shi[32][33];
  __shared__ unsigned short slo[32][33];
  const int n0 = blockIdx.x * 32, k0 = blockIdx.y * 32;
  const int ty = threadIdx.x >> 3;   // 0..31
  const int tx = threadIdx.x & 7;    // 0..7
  const float4 w4 = *(const float4*)(W + (size_t)(k0 + ty) * 3072 + n0 + (tx << 2));
  const float wv[4] = {w4.x, w4.y, w4.z, w4.w};
#pragma unroll
  for (int j = 0; j < 4; ++j) {
    const unsigned short hs = f2bf(wv[j]);
    shi[ty][(tx << 2) + j] = hs;
    slo[ty][(tx << 2) + j] = f2bf(wv[j] - bf2f(hs));
  }
  __syncthreads();
  const int n = n0 + ty;
  const ushort4 h = make_ushort4(shi[(tx << 2) + 0][ty], shi[(tx << 2) + 1][ty],
                                 shi[(tx << 2) + 2][ty], shi[(tx << 2) + 3][ty]);
  const ushort4 l = make_ushort4(slo[(tx << 2) + 0][ty], slo[(tx << 2) + 1][ty],
                                 slo[(tx << 2) + 2][ty], slo[(tx << 2) + 3][ty]);
  ushort4* row = (ushort4*)(Bt + (size_t)n * 3072);
  row[(k0 >> 2) + tx] = h;               // region 0: Wh
  row[256 + (k0 >> 2) + tx] = l;         // region 1: Wl
  row[512 + (k0 >> 2) + tx] = h;         // region 2: Wh
}

// ---------------- K1: C = A3[4096x3072] @ B3t^T + bias -> scatter Q/K/V ----------------
// m97-style: 128x128 tile, BK=32, global_load_lds(16), ds_read_b128, mfma 16x16x32 bf16
__global__ __launch_bounds__(256) void k_qkv_mfma(
    const unsigned short* __restrict__ A, const unsigned short* __restrict__ Bt,
    const float* __restrict__ bias,
    float* __restrict__ Q, float* __restrict__ Kb, float* __restrict__ V) {
  const int Kp = 3072;
  __shared__ unsigned short As[128 * 32];
  __shared__ unsigned short Bs[128 * 32];
  const int tid = threadIdx.x;
  const int lane = tid & 63;
  const int w = tid >> 6;
  const int m0 = blockIdx.y * 128, n0 = blockIdx.x * 128;
  const int wr = (w >> 1) << 6, wc = (w & 1) << 6;   // wave's 64x64 quadrant

  f32x4 acc[4][4];
#pragma unroll
  for (int i = 0; i < 4; ++i)
#pragma unroll
    for (int j = 0; j < 4; ++j) acc[i][j] = (f32x4){0.f, 0.f, 0.f, 0.f};

  // staging: load L covers 16 rows (1KB); wave w does L=2w,2w+1 for A and B
  const int lrow = lane >> 2;          // 0..15
  const int lk = (lane & 3) << 3;      // 0,8,16,24
  const unsigned short* ga0 = A + (size_t)(m0 + (w << 5) + lrow) * Kp + lk;
  const unsigned short* ga1 = A + (size_t)(m0 + (w << 5) + 16 + lrow) * Kp + lk;
  const unsigned short* gb0 = Bt + (size_t)(n0 + (w << 5) + lrow) * Kp + lk;
  const unsigned short* gb1 = Bt + (size_t)(n0 + (w << 5) + 16 + lrow) * Kp + lk;
  unsigned short* la0 = As + (w << 10) + (lane << 3);          // bytes: 2048w + 16*lane
  unsigned short* la1 = As + (w << 10) + 512 + (lane << 3);
  unsigned short* lb0 = Bs + (w << 10) + (lane << 3);
  unsigned short* lb1 = Bs + (w << 10) + 512 + (lane << 3);

  const int fcol = lane & 15;
  const int koff = (lane >> 4) << 3;

  for (int k0 = 0; k0 < Kp; k0 += 32) {
    __syncthreads();
    gl_lds16(ga0 + k0, la0);
    gl_lds16(ga1 + k0, la1);
    gl_lds16(gb0 + k0, lb0);
    gl_lds16(gb1 + k0, lb1);
    __syncthreads();   // compiler emits vmcnt(0) drain before s_barrier
    bf16x8 af[4], bfr[4];
#pragma unroll
    for (int i = 0; i < 4; ++i)
      af[i] = *(const bf16x8*)&As[((wr + (i << 4) + fcol) << 5) + koff];
#pragma unroll
    for (int j = 0; j < 4; ++j)
      bfr[j] = *(const bf16x8*)&Bs[((wc + (j << 4) + fcol) << 5) + koff];
#pragma unroll
    for (int i = 0; i < 4; ++i)
#pragma unroll
      for (int j = 0; j < 4; ++j)
        acc[i][j] = __builtin_amdgcn_mfma_f32_16x16x32_bf16(af[i], bfr[j], acc[i][j], 0, 0, 0);
  }

  // epilogue: C/D layout col=lane&15, row=(lane>>4)*4+reg
  const int qd = lane >> 4;
#pragma unroll
  for (int j = 0; j < 4; ++j) {
    const int n = n0 + wc + (j << 4) + fcol;
    const float bv = bias[n];
    const int which = n >> 10;
    const int c = n & 1023;
    const int hsel = c >> 6, cc = c & 63;
#pragma unroll
    for (int i = 0; i < 4; ++i) {
#pragma unroll
      for (int r = 0; r < 4; ++r) {
        const int m = m0 + wr + (i << 4) + (qd << 2) + r;
        const int b = m >> 10, t = m & 1023;
        const float v = acc[i][j][r] + bv;
        const size_t dst = ((size_t)((b * NH + hsel) * T_SEQ + t) << 6) + cc;
        if (which == 0) Q[dst] = v;
        else if (which == 1) Kb[dst] = v;
        else V[dst] = v;
      }
    }
  }
}

// ---------------- K2: ATT[z] = Q[z] @ K[z]^T * 0.125 (z = b*16+h) ----------------
__global__ __launch_bounds__(256) void k_att(
    const float* __restrict__ Q, const float* __restrict__ Kb, float* __restrict__ ATT) {
  __shared__ float As[16][132];
  __shared__ float Bs[16][132];
  const int tid = threadIdx.x;
  const int z = blockIdx.z;
  const float* Qz = Q + (size_t)z * T_SEQ * HD;
  const float* Kz = Kb + (size_t)z * T_SEQ * HD;
  float* Az = ATT + (size_t)z * T_SEQ * T_SEQ;
  const int m0 = blockIdx.y * 128, n0 = blockIdx.x * 128;
  const int ty = tid >> 4, tx = tid & 15;
  float acc[8][8];
#pragma unroll
  for (int i = 0; i < 8; ++i)
#pragma unroll
    for (int j = 0; j < 8; ++j) acc[i][j] = 0.f;

  const int lrow = tid >> 2, lcol = (tid & 3) << 2;

  for (int k0 = 0; k0 < HD; k0 += 16) {
#pragma unroll
    for (int r = 0; r < 2; ++r) {
      const int row = lrow + (r << 6);
      const float4 a = *(const float4*)(Qz + (size_t)(m0 + row) * HD + (k0 + lcol));
      As[lcol + 0][row] = a.x; As[lcol + 1][row] = a.y;
      As[lcol + 2][row] = a.z; As[lcol + 3][row] = a.w;
      const float4 b = *(const float4*)(Kz + (size_t)(n0 + row) * HD + (k0 + lcol));
      Bs[lcol + 0][row] = b.x; Bs[lcol + 1][row] = b.y;
      Bs[lcol + 2][row] = b.z; Bs[lcol + 3][row] = b.w;
    }
    __syncthreads();
#pragma unroll
    for (int kk = 0; kk < 16; ++kk) {
      const float4 a0 = *(const float4*)&As[kk][ty << 3];
      const float4 a1 = *(const float4*)&As[kk][(ty << 3) + 4];
      const float4 b0 = *(const float4*)&Bs[kk][tx << 3];
      const float4 b1 = *(const float4*)&Bs[kk][(tx << 3) + 4];
      const float av[8] = {a0.x, a0.y, a0.z, a0.w, a1.x, a1.y, a1.z, a1.w};
      const float bv[8] = {b0.x, b0.y, b0.z, b0.w, b1.x, b1.y, b1.z, b1.w};
#pragma unroll
      for (int i = 0; i < 8; ++i)
#pragma unroll
        for (int j = 0; j < 8; ++j) acc[i][j] = fmaf(av[i], bv[j], acc[i][j]);
    }
    __syncthreads();
  }
#pragma unroll
  for (int i = 0; i < 8; ++i)
#pragma unroll
    for (int j = 0; j < 8; ++j)
      Az[(size_t)(m0 + (ty << 3) + i) * T_SEQ + (n0 + (tx << 3) + j)] = acc[i][j] * 0.125f;
}

// ---------------- K3: per-row gumbel top-k select + double softmax ----------------
// One wave per row. Zero LDS, zero barriers. Lane owns 16 cols: col(s,j)=s*256+lane*4+j.
__global__ __launch_bounds__(256) void k_select(
    const float* __restrict__ ATT, float* __restrict__ P,
    const float* __restrict__ NOISE,
    const float* __restrict__ SR, const float* __restrict__ GT) {
  const int tid = threadIdx.x;
  const int lane = tid & 63;
  const int row = (blockIdx.x << 2) | (tid >> 6);
  const int t = row & 1023;
  const int h = (row >> 10) & 15;

  const float ratio = 1.f / (1.f + __expf(-SR[h]));
  const float temp = log1pf(__expf(GT[h])) + 0.1f;
  const float invtemp = 1.f / temp;
  const int kf = (int)floorf((float)(t + 1) * ratio);
  const unsigned k = (unsigned)(kf < 1 ? 1 : kf);

  const float4* arow = (const float4*)(ATT + ((size_t)row << 10));
  const float4* urow = (const float4*)(NOISE + ((size_t)row << 10));

  float av[16], gv[16];
  unsigned key[16];
#pragma unroll
  for (int s = 0; s < 4; ++s) {
    const float4 a4 = arow[(s << 6) + lane];
    const float4 u4 = urow[(s << 6) + lane];
    const float aa[4] = {a4.x, a4.y, a4.z, a4.w};
    const float uu[4] = {u4.x, u4.y, u4.z, u4.w};
#pragma unroll
    for (int j = 0; j < 4; ++j) {
      const int e = (s << 2) + j;
      const int col = (s << 8) + (lane << 2) + j;
      const float g = -__logf(-__logf(uu[j] + 1e-8f) + 1e-8f);
      av[e] = aa[j];
      gv[e] = (col <= t) ? (aa[j] + g) * invtemp : -INFINITY;
      key[e] = fkey(gv[e]);
    }
  }

  // bitwise binary search for tau = k-th largest key (exact)
  unsigned th = 0u;
#pragma unroll
  for (int b = 31; b >= 0; --b) {
    const unsigned cand = th | (1u << b);
    unsigned c = 0;
#pragma unroll
    for (int e = 0; e < 16; ++e)
      c += (unsigned)__popcll(__ballot(key[e] >= cand));
    if (c >= k) th = cand;
  }
  const unsigned tau = th;

  unsigned cnt_gt = 0;
#pragma unroll
  for (int e = 0; e < 16; ++e)
    cnt_gt += (unsigned)__popcll(__ballot(key[e] > tau));
  const unsigned need = k - cnt_gt;

  const unsigned long long below = ((unsigned long long)1 << lane) - 1ull;
  unsigned rank[16];
  unsigned base = 0;
#pragma unroll
  for (int s = 0; s < 4; ++s) {
    unsigned lanecnt = 0, tot = 0, own = 0;
    unsigned long long B[4];
#pragma unroll
    for (int j = 0; j < 4; ++j) {
      B[j] = __ballot(key[(s << 2) + j] == tau);
      lanecnt += (unsigned)__popcll(B[j] & below);
      tot += (unsigned)__popcll(B[j]);
    }
#pragma unroll
    for (int j = 0; j < 4; ++j) {
      rank[(s << 2) + j] = base + lanecnt + own;
      own += (key[(s << 2) + j] == tau) ? 1u : 0u;
    }
    base += tot;
  }

  bool sel[16];
#pragma unroll
  for (int e = 0; e < 16; ++e)
    sel[e] = (key[e] > tau) | ((key[e] == tau) & (rank[e] < need));

  float lm = -INFINITY;
#pragma unroll
  for (int e = 0; e < 16; ++e) lm = fmaxf(lm, gv[e]);
  const float m = wredmax(lm);

  float ex[16];
  float ps = 0.f;
#pragma unroll
  for (int e = 0; e < 16; ++e) {
    ex[e] = sel[e] ? __expf(gv[e] - m) : 0.f;
    ps += ex[e];
  }
  const float S = wredsum(ps);
  const float invS = 1.f / S;

  float sp[16];
#pragma unroll
  for (int e = 0; e < 16; ++e) sp[e] = sel[e] ? av[e] * ex[e] * invS : 0.f;

  float lM = 0.f;
#pragma unroll
  for (int e = 0; e < 16; ++e) lM = fmaxf(lM, sp[e]);
  const float M = wredmax(lM);

  float pe[16];
  float lz = 0.f;
#pragma unroll
  for (int e = 0; e < 16; ++e) { pe[e] = __expf(sp[e] - M); lz += pe[e]; }
  const float Z = wredsum(lz);
  const float invZ = 1.f / Z;

  float4* prow = (float4*)(P + ((size_t)row << 10));
#pragma unroll
  for (int s = 0; s < 4; ++s)
    prow[(s << 6) + lane] = make_float4(pe[(s << 2) + 0] * invZ, pe[(s << 2) + 1] * invZ,
                                        pe[(s << 2) + 2] * invZ, pe[(s << 2) + 3] * invZ);
}

// ---------------- K4: Y[b,t,h*64+d] = sum_k P[z,t,k] * V[z,k,d] ----------------
__global__ __launch_bounds__(256) void k_pv(
    const float* __restrict__ P, const float* __restrict__ V, float* __restrict__ Y) {
  __shared__ float As[32][68];
  __shared__ float Bs[32][68];
  const int tid = threadIdx.x;
  const int z = blockIdx.z;
  const int b = z >> 4, h = z & 15;
  const float* Pz = P + (size_t)z * T_SEQ * T_SEQ;
  const float* Vz = V + (size_t)z * T_SEQ * HD;
  const int m0 = blockIdx.x * 64;
  const int ty = tid >> 4, tx = tid & 15;
  float acc[4][4];
#pragma unroll
  for (int i = 0; i < 4; ++i)
#pragma unroll
    for (int j = 0; j < 4; ++j) acc[i][j] = 0.f;

  const int prow = tid >> 3, pcol = (tid & 7) << 2;
  const int vrow = tid >> 4, vcol = (tid & 15) << 2;

  for (int k0 = 0; k0 < T_SEQ; k0 += 32) {
#pragma unroll
    for (int r = 0; r < 2; ++r) {
      const int row = prow + (r << 5);
      const float4 a = *(const float4*)(Pz + (size_t)(m0 + row) * T_SEQ + (k0 + pcol));
      As[pcol + 0][row] = a.x; As[pcol + 1][row] = a.y;
      As[pcol + 2][row] = a.z; As[pcol + 3][row] = a.w;
      const int rowb = vrow + (r << 4);
      *(float4*)&Bs[rowb][vcol] = *(const float4*)(Vz + (size_t)(k0 + rowb) * HD + vcol);
    }
    __syncthreads();
#pragma unroll
    for (int kk = 0; kk < 32; ++kk) {
      const float4 a = *(const float4*)&As[kk][ty << 2];
      const float4 bv = *(const float4*)&Bs[kk][tx << 2];
      const float avv[4] = {a.x, a.y, a.z, a.w};
      const float bb[4] = {bv.x, bv.y, bv.z, bv.w};
#pragma unroll
      for (int i = 0; i < 4; ++i)
#pragma unroll
        for (int j = 0; j < 4; ++j) acc[i][j] = fmaf(avv[i], bb[j], acc[i][j]);
    }
    __syncthreads();
  }
#pragma unroll
  for (int i = 0; i < 4; ++i) {
    const int trow = m0 + (ty << 2) + i;
#pragma unroll
    for (int j = 0; j < 4; ++j)
      Y[((size_t)(b * T_SEQ + trow) << 10) + (h << 6) + (tx << 2) + j] = acc[i][j];
  }
}

// ---------------- K5: OUT = Y[4096,1024] @ W_proj[1024,1024] + b_proj ----------------
__global__ __launch_bounds__(256) void k_proj(
    const float* __restrict__ Yin, const float* __restrict__ W, const float* __restrict__ bias,
    float* __restrict__ OUT) {
  const int K = 1024, N = 1024;
  __shared__ float As[16][132];
  __shared__ float Bs[16][132];
  const int tid = threadIdx.x;
  const int m0 = blockIdx.y * 128;
  const int n0 = blockIdx.x * 128;
  const int ty = tid >> 4, tx = tid & 15;
  float acc[8][8];
#pragma unroll
  for (int i = 0; i < 8; ++i)
#pragma unroll
    for (int j = 0; j < 8; ++j) acc[i][j] = 0.f;

  const int arow = tid >> 2, acol = (tid & 3) << 2;
  const int brow = tid >> 5, bcol = (tid & 31) << 2;

  for (int k0 = 0; k0 < K; k0 += 16) {
#pragma unroll
    for (int r = 0; r < 2; ++r) {
      const int row = arow + (r << 6);
      const float4 a = *(const float4*)(Yin + (size_t)(m0 + row) * K + (k0 + acol));
      As[acol + 0][row] = a.x; As[acol + 1][row] = a.y;
      As[acol + 2][row] = a.z; As[acol + 3][row] = a.w;
    }
#pragma unroll
    for (int r = 0; r < 2; ++r) {
      const int row = brow + (r << 3);
      *(float4*)&Bs[row][bcol] = *(const float4*)(W + (size_t)(k0 + row) * N + (n0 + bcol));
    }
    __syncthreads();
#pragma unroll
    for (int kk = 0; kk < 16; ++kk) {
      const float4 a0 = *(const float4*)&As[kk][ty << 3];
      const float4 a1 = *(const float4*)&As[kk][(ty << 3) + 4];
      const float4 b0 = *(const float4*)&Bs[kk][tx << 3];
      const float4 b1 = *(const float4*)&Bs[kk][(tx << 3) + 4];
      const float av[8] = {a0.x, a0.y, a0.z, a0.w, a1.x, a1.y, a1.z, a1.w};
      const float bv[8] = {b0.x, b0.y, b0.z, b0.w, b1.x, b1.y, b1.z, b1.w};
#pragma unroll
      for (int i = 0; i < 8; ++i)
#pragma unroll
        for (int j = 0; j < 8; ++j) acc[i][j] = fmaf(av[i], bv[j], acc[i][j]);
    }
    __syncthreads();
  }
#pragma unroll
  for (int i = 0; i < 8; ++i) {
    const int m = m0 + (ty << 3) + i;
#pragma unroll
    for (int j = 0; j < 8; ++j) {
      const int n = n0 + (tx << 3) + j;
      OUT[(size_t)m * N + n] = acc[i][j] + bias[n];
    }
  }
}

extern "C" void kernel_launch(void* const* d_in, const int* in_sizes, int n_in,
                              void* d_out, int out_size, void* d_ws, size_t ws_size,
                              hipStream_t stream) {
  const float* x      = (const float*)d_in[0];
  const float* W_attn = (const float*)d_in[1];
  const float* b_attn = (const float*)d_in[2];
  const float* W_proj = (const float*)d_in[3];
  const float* b_proj = (const float*)d_in[4];
  const float* sr     = (const float*)d_in[5];
  const float* gt     = (const float*)d_in[6];
  const float* noise  = (const float*)d_in[7];

  float* ws  = (float*)d_ws;
  float* Q   = ws;               // 4,194,304 floats
  float* K   = ws + 4194304;
  float* V   = ws + 8388608;
  float* ATT = ws + 12582912;    // 67,108,864 floats (reused as P in-place)
  float* Y   = ws + 79691776;    // 4,194,304 floats
  float* OUT = (float*)d_out;

  // A3/B3t alias the ATT region (consumed by k_qkv_mfma before k_att writes ATT)
  unsigned short* A3  = (unsigned short*)ATT;              // 4096*3072 shorts
  unsigned short* B3t = (unsigned short*)ATT + 12582912;   // 3072*3072 shorts

  k_split_a <<<dim3(4096),    256, 0, stream>>>(x, A3);
  k_split_bt<<<dim3(96, 32),  256, 0, stream>>>(W_attn, B3t);
  k_qkv_mfma<<<dim3(24, 32),  256, 0, stream>>>(A3, B3t, b_attn, Q, K, V);
  k_att  <<<dim3(8, 8, 64), 256, 0, stream>>>(Q, K, ATT);
  k_select<<<dim3(16384),   256, 0, stream>>>(ATT, ATT, noise, sr, gt);
  k_pv   <<<dim3(16, 1, 64),256, 0, stream>>>(ATT, V, Y);
  k_proj <<<dim3(8, 32),    256, 0, stream>>>(Y, W_proj, b_proj, OUT);
}

// Round 4
// 849.517 us; speedup vs baseline: 1.8972x; 1.2324x over previous
//
#include <hip/hip_runtime.h>
#include <math.h>

#define T_SEQ 1024
#define NH 16
#define HD 64

typedef __attribute__((ext_vector_type(8))) short bf16x8;
typedef __attribute__((ext_vector_type(4))) float f32x4;

// monotone float -> uint key: a<b (float) <=> fkey(a)<fkey(b) (uint)
__device__ __forceinline__ unsigned fkey(float x) {
  unsigned u = __float_as_uint(x);
  return (u & 0x80000000u) ? ~u : (u | 0x80000000u);
}

__device__ __forceinline__ float wredmax(float v) {
#pragma unroll
  for (int m = 1; m < 64; m <<= 1) v = fmaxf(v, __shfl_xor(v, m));
  return v;
}
__device__ __forceinline__ float wredsum(float v) {
#pragma unroll
  for (int m = 1; m < 64; m <<= 1) v += __shfl_xor(v, m);
  return v;
}

// fp32 -> bf16 round-to-nearest-even (finite inputs)
__device__ __forceinline__ unsigned short f2bf(float f) {
  unsigned u = __float_as_uint(f);
  return (unsigned short)((u + 0x7fffu + ((u >> 16) & 1u)) >> 16);
}
__device__ __forceinline__ float bf2f(unsigned short h) {
  return __uint_as_float(((unsigned)h) << 16);
}

// async global->LDS, 16B/lane (LDS dest = wave-uniform base + lane*16)
__device__ __forceinline__ void gl_lds16(const void* g, void* l) {
  __builtin_amdgcn_global_load_lds(
      (const __attribute__((address_space(1))) unsigned int*)g,
      (__attribute__((address_space(3))) unsigned int*)l,
      16, 0, 0);
}

// ---------------- P1: A2 = [hi(X) | lo(X)]  [4096][2048] bf16 ----------------
__global__ __launch_bounds__(256) void k_split_a2(const float* __restrict__ X,
                                                  unsigned short* __restrict__ A2) {
  const int idx = blockIdx.x * 256 + threadIdx.x;   // float4 index
  const int m = idx >> 8;
  const int c4 = idx & 255;
  const float4 x = ((const float4*)(X + ((size_t)m << 10)))[c4];
  const float xs[4] = {x.x, x.y, x.z, x.w};
  unsigned short hh[4], ll[4];
#pragma unroll
  for (int j = 0; j < 4; ++j) {
    hh[j] = f2bf(xs[j]);
    ll[j] = f2bf(xs[j] - bf2f(hh[j]));
  }
  ushort4* dst = (ushort4*)(A2 + ((size_t)m << 11));
  dst[c4] = make_ushort4(hh[0], hh[1], hh[2], hh[3]);
  dst[c4 + 256] = make_ushort4(ll[0], ll[1], ll[2], ll[3]);
}

// ---------------- P2: W[K][N] -> Bh[N][K]=hi(W)^T, Bl[N][K]=lo(W)^T ----------------
__global__ __launch_bounds__(256) void k_split_b2(const float* __restrict__ W,
                                                  unsigned short* __restrict__ Bh,
                                                  unsigned short* __restrict__ Bl,
                                                  int N, int K) {
  __shared__ unsigned short shi[32][33];
  __shared__ unsigned short slo[32][33];
  const int n0 = blockIdx.x * 32, k0 = blockIdx.y * 32;
  const int ty = threadIdx.x >> 3;   // 0..31
  const int tx = threadIdx.x & 7;    // 0..7
  const float4 w4 = *(const float4*)(W + (size_t)(k0 + ty) * N + n0 + (tx << 2));
  const float wv[4] = {w4.x, w4.y, w4.z, w4.w};
#pragma unroll
  for (int j = 0; j < 4; ++j) {
    const unsigned short hs = f2bf(wv[j]);
    shi[ty][(tx << 2) + j] = hs;
    slo[ty][(tx << 2) + j] = f2bf(wv[j] - bf2f(hs));
  }
  __syncthreads();
  const int n = n0 + ty;
  const ushort4 h = make_ushort4(shi[(tx << 2) + 0][ty], shi[(tx << 2) + 1][ty],
                                 shi[(tx << 2) + 2][ty], shi[(tx << 2) + 3][ty]);
  const ushort4 l = make_ushort4(slo[(tx << 2) + 0][ty], slo[(tx << 2) + 1][ty],
                                 slo[(tx << 2) + 2][ty], slo[(tx << 2) + 3][ty]);
  ((ushort4*)(Bh + (size_t)n * K))[(k0 >> 2) + tx] = h;
  ((ushort4*)(Bl + (size_t)n * K))[(k0 >> 2) + tx] = l;
}

// ---------------- K1: QKV = A2 @ [Bh+Bl]^T + bias -> split-bf16 Q2/K/V ----------------
// 128x128 tile, BK=32, 3-term MFMA: Ah*Bh + Ah*Bl + Al*Bh
__global__ __launch_bounds__(256) void k_qkv3(
    const unsigned short* __restrict__ A, const unsigned short* __restrict__ Bh,
    const unsigned short* __restrict__ Bl, const float* __restrict__ bias,
    unsigned short* __restrict__ Q2, unsigned short* __restrict__ Kht,
    unsigned short* __restrict__ Klt, unsigned short* __restrict__ Vht,
    unsigned short* __restrict__ Vlt) {
  __shared__ unsigned short Ahs[128 * 32], Als[128 * 32], Bhs[128 * 32], Bls[128 * 32];
  const int tid = threadIdx.x, lane = tid & 63, w = tid >> 6;
  const int m0 = blockIdx.y * 128, n0 = blockIdx.x * 128;
  const int wr = (w >> 1) << 6, wc = (w & 1) << 6;
  f32x4 acc[4][4];
#pragma unroll
  for (int i = 0; i < 4; ++i)
#pragma unroll
    for (int j = 0; j < 4; ++j) acc[i][j] = (f32x4){0.f, 0.f, 0.f, 0.f};

  const int lrow = lane >> 2, lk = (lane & 3) << 3;
  const int r0 = (w << 5) + lrow, r1 = r0 + 16;
  const unsigned short* gah0 = A + (size_t)(m0 + r0) * 2048 + lk;
  const unsigned short* gah1 = A + (size_t)(m0 + r1) * 2048 + lk;
  const unsigned short* gbh0 = Bh + (size_t)(n0 + r0) * 1024 + lk;
  const unsigned short* gbh1 = Bh + (size_t)(n0 + r1) * 1024 + lk;
  const unsigned short* gbl0 = Bl + (size_t)(n0 + r0) * 1024 + lk;
  const unsigned short* gbl1 = Bl + (size_t)(n0 + r1) * 1024 + lk;
  unsigned short* lah0 = Ahs + (w << 10) + (lane << 3);
  unsigned short* lal0 = Als + (w << 10) + (lane << 3);
  unsigned short* lbh0 = Bhs + (w << 10) + (lane << 3);
  unsigned short* lbl0 = Bls + (w << 10) + (lane << 3);
  const int fcol = lane & 15, koff = (lane >> 4) << 3;

  for (int k0 = 0; k0 < 1024; k0 += 32) {
    __syncthreads();
    gl_lds16(gah0 + k0, lah0);        gl_lds16(gah1 + k0, lah0 + 512);
    gl_lds16(gah0 + 1024 + k0, lal0); gl_lds16(gah1 + 1024 + k0, lal0 + 512);
    gl_lds16(gbh0 + k0, lbh0);        gl_lds16(gbh1 + k0, lbh0 + 512);
    gl_lds16(gbl0 + k0, lbl0);        gl_lds16(gbl1 + k0, lbl0 + 512);
    __syncthreads();
    bf16x8 afh[4], afl[4], bfh[4], bfl[4];
#pragma unroll
    for (int i = 0; i < 4; ++i) {
      const int off = ((wr + (i << 4) + fcol) << 5) + koff;
      afh[i] = *(const bf16x8*)&Ahs[off];
      afl[i] = *(const bf16x8*)&Als[off];
    }
#pragma unroll
    for (int j = 0; j < 4; ++j) {
      const int off = ((wc + (j << 4) + fcol) << 5) + koff;
      bfh[j] = *(const bf16x8*)&Bhs[off];
      bfl[j] = *(const bf16x8*)&Bls[off];
    }
#pragma unroll
    for (int i = 0; i < 4; ++i)
#pragma unroll
      for (int j = 0; j < 4; ++j) {
        acc[i][j] = __builtin_amdgcn_mfma_f32_16x16x32_bf16(afh[i], bfh[j], acc[i][j], 0, 0, 0);
        acc[i][j] = __builtin_amdgcn_mfma_f32_16x16x32_bf16(afh[i], bfl[j], acc[i][j], 0, 0, 0);
        acc[i][j] = __builtin_amdgcn_mfma_f32_16x16x32_bf16(afl[i], bfh[j], acc[i][j], 0, 0, 0);
      }
  }

  const int qd = lane >> 4;
#pragma unroll
  for (int j = 0; j < 4; ++j) {
    const int n = n0 + wc + (j << 4) + fcol;
    const float bv = bias[n];
    const int which = n >> 10;
    const int c = n & 1023;
    const int hsel = c >> 6, cc = c & 63;
#pragma unroll
    for (int i = 0; i < 4; ++i) {
#pragma unroll
      for (int r = 0; r < 4; ++r) {
        const int m = m0 + wr + (i << 4) + (qd << 2) + r;
        const int b = m >> 10, t = m & 1023;
        const int z = b * NH + hsel;
        const float v = acc[i][j][r] + bv;
        const unsigned short hi = f2bf(v);
        const unsigned short lo = f2bf(v - bf2f(hi));
        if (which == 0) {            // Q2[z][t][128] = [Qh|Ql]
          unsigned short* q = Q2 + (((size_t)z * T_SEQ + t) << 7) + cc;
          q[0] = hi; q[64] = lo;
        } else if (which == 1) {     // Kht/Klt[z][t][64]
          const size_t o = (((size_t)z * T_SEQ + t) << 6) + cc;
          Kht[o] = hi; Klt[o] = lo;
        } else {                     // Vht/Vlt[z][d][1024] (transposed)
          const size_t o = (((size_t)z * HD + cc) << 10) + t;
          Vht[o] = hi; Vlt[o] = lo;
        }
      }
    }
  }
}

// ---------------- K2: ATT[z] = (Q2 @ K^T) * 0.125, K=64, 2 K-iters ----------------
__global__ __launch_bounds__(256) void k_att3(
    const unsigned short* __restrict__ Q2, const unsigned short* __restrict__ Kht,
    const unsigned short* __restrict__ Klt, float* __restrict__ ATT) {
  __shared__ unsigned short Ahs[128 * 32], Als[128 * 32], Bhs[128 * 32], Bls[128 * 32];
  const int tid = threadIdx.x, lane = tid & 63, w = tid >> 6;
  const int z = blockIdx.z;
  const unsigned short* A = Q2 + ((size_t)z * T_SEQ << 7);
  const unsigned short* Bh = Kht + ((size_t)z * T_SEQ << 6);
  const unsigned short* Bl = Klt + ((size_t)z * T_SEQ << 6);
  float* Az = ATT + (size_t)z * T_SEQ * T_SEQ;
  const int m0 = blockIdx.y * 128, n0 = blockIdx.x * 128;
  const int wr = (w >> 1) << 6, wc = (w & 1) << 6;
  f32x4 acc[4][4];
#pragma unroll
  for (int i = 0; i < 4; ++i)
#pragma unroll
    for (int j = 0; j < 4; ++j) acc[i][j] = (f32x4){0.f, 0.f, 0.f, 0.f};

  const int lrow = lane >> 2, lk = (lane & 3) << 3;
  const int r0 = (w << 5) + lrow, r1 = r0 + 16;
  const unsigned short* gah0 = A + ((size_t)(m0 + r0) << 7) + lk;
  const unsigned short* gah1 = A + ((size_t)(m0 + r1) << 7) + lk;
  const unsigned short* gbh0 = Bh + ((size_t)(n0 + r0) << 6) + lk;
  const unsigned short* gbh1 = Bh + ((size_t)(n0 + r1) << 6) + lk;
  const unsigned short* gbl0 = Bl + ((size_t)(n0 + r0) << 6) + lk;
  const unsigned short* gbl1 = Bl + ((size_t)(n0 + r1) << 6) + lk;
  unsigned short* lah0 = Ahs + (w << 10) + (lane << 3);
  unsigned short* lal0 = Als + (w << 10) + (lane << 3);
  unsigned short* lbh0 = Bhs + (w << 10) + (lane << 3);
  unsigned short* lbl0 = Bls + (w << 10) + (lane << 3);
  const int fcol = lane & 15, koff = (lane >> 4) << 3;

#pragma unroll
  for (int k0 = 0; k0 < 64; k0 += 32) {
    __syncthreads();
    gl_lds16(gah0 + k0, lah0);      gl_lds16(gah1 + k0, lah0 + 512);
    gl_lds16(gah0 + 64 + k0, lal0); gl_lds16(gah1 + 64 + k0, lal0 + 512);
    gl_lds16(gbh0 + k0, lbh0);      gl_lds16(gbh1 + k0, lbh0 + 512);
    gl_lds16(gbl0 + k0, lbl0);      gl_lds16(gbl1 + k0, lbl0 + 512);
    __syncthreads();
    bf16x8 afh[4], afl[4], bfh[4], bfl[4];
#pragma unroll
    for (int i = 0; i < 4; ++i) {
      const int off = ((wr + (i << 4) + fcol) << 5) + koff;
      afh[i] = *(const bf16x8*)&Ahs[off];
      afl[i] = *(const bf16x8*)&Als[off];
    }
#pragma unroll
    for (int j = 0; j < 4; ++j) {
      const int off = ((wc + (j << 4) + fcol) << 5) + koff;
      bfh[j] = *(const bf16x8*)&Bhs[off];
      bfl[j] = *(const bf16x8*)&Bls[off];
    }
#pragma unroll
    for (int i = 0; i < 4; ++i)
#pragma unroll
      for (int j = 0; j < 4; ++j) {
        acc[i][j] = __builtin_amdgcn_mfma_f32_16x16x32_bf16(afh[i], bfh[j], acc[i][j], 0, 0, 0);
        acc[i][j] = __builtin_amdgcn_mfma_f32_16x16x32_bf16(afh[i], bfl[j], acc[i][j], 0, 0, 0);
        acc[i][j] = __builtin_amdgcn_mfma_f32_16x16x32_bf16(afl[i], bfh[j], acc[i][j], 0, 0, 0);
      }
  }

  const int qd = lane >> 4;
#pragma unroll
  for (int i = 0; i < 4; ++i)
#pragma unroll
    for (int r = 0; r < 4; ++r) {
      const int m = wr + (i << 4) + (qd << 2) + r;
#pragma unroll
      for (int j = 0; j < 4; ++j)
        Az[(size_t)(m0 + m) * T_SEQ + (n0 + wc + (j << 4) + fcol)] = acc[i][j][r] * 0.125f;
    }
}

// ---------------- K3: per-row gumbel top-k select + double softmax ----------------
// One wave per row, in-register; writes P IN PLACE as bf16 [Ph|Pl] (2048 cols).
__global__ __launch_bounds__(256) void k_select(
    const float* __restrict__ ATT, unsigned short* __restrict__ P2,
    const float* __restrict__ NOISE,
    const float* __restrict__ SR, const float* __restrict__ GT) {
  const int tid = threadIdx.x;
  const int lane = tid & 63;
  const int row = (blockIdx.x << 2) | (tid >> 6);
  const int t = row & 1023;
  const int h = (row >> 10) & 15;

  const float ratio = 1.f / (1.f + __expf(-SR[h]));
  const float temp = log1pf(__expf(GT[h])) + 0.1f;
  const float invtemp = 1.f / temp;
  const int kf = (int)floorf((float)(t + 1) * ratio);
  const unsigned k = (unsigned)(kf < 1 ? 1 : kf);

  const float4* arow = (const float4*)(ATT + ((size_t)row << 10));
  const float4* urow = (const float4*)(NOISE + ((size_t)row << 10));

  float av[16], gv[16];
  unsigned key[16];
#pragma unroll
  for (int s = 0; s < 4; ++s) {
    const float4 a4 = arow[(s << 6) + lane];
    const float4 u4 = urow[(s << 6) + lane];
    const float aa[4] = {a4.x, a4.y, a4.z, a4.w};
    const float uu[4] = {u4.x, u4.y, u4.z, u4.w};
#pragma unroll
    for (int j = 0; j < 4; ++j) {
      const int e = (s << 2) + j;
      const int col = (s << 8) + (lane << 2) + j;
      const float g = -__logf(-__logf(uu[j] + 1e-8f) + 1e-8f);
      av[e] = aa[j];
      gv[e] = (col <= t) ? (aa[j] + g) * invtemp : -INFINITY;
      key[e] = fkey(gv[e]);
    }
  }

  // bitwise binary search for tau = k-th largest key (exact)
  unsigned th = 0u;
#pragma unroll
  for (int b = 31; b >= 0; --b) {
    const unsigned cand = th | (1u << b);
    unsigned c = 0;
#pragma unroll
    for (int e = 0; e < 16; ++e)
      c += (unsigned)__popcll(__ballot(key[e] >= cand));
    if (c >= k) th = cand;
  }
  const unsigned tau = th;

  unsigned cnt_gt = 0;
#pragma unroll
  for (int e = 0; e < 16; ++e)
    cnt_gt += (unsigned)__popcll(__ballot(key[e] > tau));
  const unsigned need = k - cnt_gt;

  const unsigned long long below = ((unsigned long long)1 << lane) - 1ull;
  unsigned rank[16];
  unsigned base = 0;
#pragma unroll
  for (int s = 0; s < 4; ++s) {
    unsigned lanecnt = 0, tot = 0, own = 0;
    unsigned long long B[4];
#pragma unroll
    for (int j = 0; j < 4; ++j) {
      B[j] = __ballot(key[(s << 2) + j] == tau);
      lanecnt += (unsigned)__popcll(B[j] & below);
      tot += (unsigned)__popcll(B[j]);
    }
#pragma unroll
    for (int j = 0; j < 4; ++j) {
      rank[(s << 2) + j] = base + lanecnt + own;
      own += (key[(s << 2) + j] == tau) ? 1u : 0u;
    }
    base += tot;
  }

  bool sel[16];
#pragma unroll
  for (int e = 0; e < 16; ++e)
    sel[e] = (key[e] > tau) | ((key[e] == tau) & (rank[e] < need));

  float lm = -INFINITY;
#pragma unroll
  for (int e = 0; e < 16; ++e) lm = fmaxf(lm, gv[e]);
  const float m = wredmax(lm);

  float ex[16];
  float ps = 0.f;
#pragma unroll
  for (int e = 0; e < 16; ++e) {
    ex[e] = sel[e] ? __expf(gv[e] - m) : 0.f;
    ps += ex[e];
  }
  const float S = wredsum(ps);
  const float invS = 1.f / S;

  float sp[16];
#pragma unroll
  for (int e = 0; e < 16; ++e) sp[e] = sel[e] ? av[e] * ex[e] * invS : 0.f;

  float lM = 0.f;
#pragma unroll
  for (int e = 0; e < 16; ++e) lM = fmaxf(lM, sp[e]);
  const float M = wredmax(lM);

  float pe[16];
  float lz = 0.f;
#pragma unroll
  for (int e = 0; e < 16; ++e) { pe[e] = __expf(sp[e] - M); lz += pe[e]; }
  const float Z = wredsum(lz);
  const float invZ = 1.f / Z;

  // write split-bf16 [Ph|Pl] in place (2048 shorts == 1024 floats of the ATT row)
  ushort4* prow = (ushort4*)(P2 + ((size_t)row << 11));
#pragma unroll
  for (int s = 0; s < 4; ++s) {
    unsigned short hh[4], ll[4];
#pragma unroll
    for (int j = 0; j < 4; ++j) {
      const float p = pe[(s << 2) + j] * invZ;
      hh[j] = f2bf(p);
      ll[j] = f2bf(p - bf2f(hh[j]));
    }
    prow[(s << 6) + lane] = make_ushort4(hh[0], hh[1], hh[2], hh[3]);
    prow[256 + (s << 6) + lane] = make_ushort4(ll[0], ll[1], ll[2], ll[3]);
  }
}

// ---------------- K4: Y2 = P2 @ V (128x64 tile), epilogue writes split Y2 ----------------
__global__ __launch_bounds__(256) void k_pv3(
    const unsigned short* __restrict__ P2, const unsigned short* __restrict__ Vht,
    const unsigned short* __restrict__ Vlt, unsigned short* __restrict__ Y2) {
  __shared__ unsigned short Ahs[128 * 32], Als[128 * 32], Bhs[64 * 32], Bls[64 * 32];
  const int tid = threadIdx.x, lane = tid & 63, w = tid >> 6;
  const int z = blockIdx.z;
  const int b = z >> 4, h = z & 15;
  const unsigned short* A = P2 + ((size_t)z * T_SEQ << 11);
  const unsigned short* Bh = Vht + ((size_t)z * HD << 10);
  const unsigned short* Bl = Vlt + ((size_t)z * HD << 10);
  const int m0 = blockIdx.x * 128;
  const int wr = (w >> 1) << 6, wc = (w & 1) << 5;
  f32x4 acc[4][2];
#pragma unroll
  for (int i = 0; i < 4; ++i)
#pragma unroll
    for (int j = 0; j < 2; ++j) acc[i][j] = (f32x4){0.f, 0.f, 0.f, 0.f};

  const int lrow = lane >> 2, lk = (lane & 3) << 3;
  const int ra0 = (w << 5) + lrow, ra1 = ra0 + 16;
  const int rb = (w << 4) + lrow;
  const unsigned short* gah0 = A + ((size_t)(m0 + ra0) << 11) + lk;
  const unsigned short* gah1 = A + ((size_t)(m0 + ra1) << 11) + lk;
  const unsigned short* gbh = Bh + ((size_t)rb << 10) + lk;
  const unsigned short* gbl = Bl + ((size_t)rb << 10) + lk;
  unsigned short* lah0 = Ahs + (w << 10) + (lane << 3);
  unsigned short* lal0 = Als + (w << 10) + (lane << 3);
  unsigned short* lbh = Bhs + (w << 9) + (lane << 3);
  unsigned short* lbl = Bls + (w << 9) + (lane << 3);
  const int fcol = lane & 15, koff = (lane >> 4) << 3;

  for (int k0 = 0; k0 < 1024; k0 += 32) {
    __syncthreads();
    gl_lds16(gah0 + k0, lah0);        gl_lds16(gah1 + k0, lah0 + 512);
    gl_lds16(gah0 + 1024 + k0, lal0); gl_lds16(gah1 + 1024 + k0, lal0 + 512);
    gl_lds16(gbh + k0, lbh);
    gl_lds16(gbl + k0, lbl);
    __syncthreads();
    bf16x8 afh[4], afl[4], bfh[2], bfl[2];
#pragma unroll
    for (int i = 0; i < 4; ++i) {
      const int off = ((wr + (i << 4) + fcol) << 5) + koff;
      afh[i] = *(const bf16x8*)&Ahs[off];
      afl[i] = *(const bf16x8*)&Als[off];
    }
#pragma unroll
    for (int j = 0; j < 2; ++j) {
      const int off = ((wc + (j << 4) + fcol) << 5) + koff;
      bfh[j] = *(const bf16x8*)&Bhs[off];
      bfl[j] = *(const bf16x8*)&Bls[off];
    }
#pragma unroll
    for (int i = 0; i < 4; ++i)
#pragma unroll
      for (int j = 0; j < 2; ++j) {
        acc[i][j] = __builtin_amdgcn_mfma_f32_16x16x32_bf16(afh[i], bfh[j], acc[i][j], 0, 0, 0);
        acc[i][j] = __builtin_amdgcn_mfma_f32_16x16x32_bf16(afh[i], bfl[j], acc[i][j], 0, 0, 0);
        acc[i][j] = __builtin_amdgcn_mfma_f32_16x16x32_bf16(afl[i], bfh[j], acc[i][j], 0, 0, 0);
      }
  }

  const int qd = lane >> 4;
#pragma unroll
  for (int j = 0; j < 2; ++j) {
    const int d = wc + (j << 4) + fcol;      // 0..63
    const int c = (h << 6) + d;              // col in Y
#pragma unroll
    for (int i = 0; i < 4; ++i) {
#pragma unroll
      for (int r = 0; r < 4; ++r) {
        const int tq = m0 + wr + (i << 4) + (qd << 2) + r;
        const float v = acc[i][j][r];
        const unsigned short hi = f2bf(v);
        const unsigned short lo = f2bf(v - bf2f(hi));
        unsigned short* y = Y2 + (((size_t)(b * T_SEQ + tq)) << 11) + c;
        y[0] = hi; y[1024] = lo;
      }
    }
  }
}

// ---------------- K5: OUT = Y2 @ [Wph+Wpl]^T + b_proj ----------------
__global__ __launch_bounds__(256) void k_proj3(
    const unsigned short* __restrict__ A, const unsigned short* __restrict__ Bh,
    const unsigned short* __restrict__ Bl, const float* __restrict__ bias,
    float* __restrict__ OUT) {
  __shared__ unsigned short Ahs[128 * 32], Als[128 * 32], Bhs[128 * 32], Bls[128 * 32];
  const int tid = threadIdx.x, lane = tid & 63, w = tid >> 6;
  const int m0 = blockIdx.y * 128, n0 = blockIdx.x * 128;
  const int wr = (w >> 1) << 6, wc = (w & 1) << 6;
  f32x4 acc[4][4];
#pragma unroll
  for (int i = 0; i < 4; ++i)
#pragma unroll
    for (int j = 0; j < 4; ++j) acc[i][j] = (f32x4){0.f, 0.f, 0.f, 0.f};

  const int lrow = lane >> 2, lk = (lane & 3) << 3;
  const int r0 = (w << 5) + lrow, r1 = r0 + 16;
  const unsigned short* gah0 = A + ((size_t)(m0 + r0) << 11) + lk;
  const unsigned short* gah1 = A + ((size_t)(m0 + r1) << 11) + lk;
  const unsigned short* gbh0 = Bh + ((size_t)(n0 + r0) << 10) + lk;
  const unsigned short* gbh1 = Bh + ((size_t)(n0 + r1) << 10) + lk;
  const unsigned short* gbl0 = Bl + ((size_t)(n0 + r0) << 10) + lk;
  const unsigned short* gbl1 = Bl + ((size_t)(n0 + r1) << 10) + lk;
  unsigned short* lah0 = Ahs + (w << 10) + (lane << 3);
  unsigned short* lal0 = Als + (w << 10) + (lane << 3);
  unsigned short* lbh0 = Bhs + (w << 10) + (lane << 3);
  unsigned short* lbl0 = Bls + (w << 10) + (lane << 3);
  const int fcol = lane & 15, koff = (lane >> 4) << 3;

  for (int k0 = 0; k0 < 1024; k0 += 32) {
    __syncthreads();
    gl_lds16(gah0 + k0, lah0);        gl_lds16(gah1 + k0, lah0 + 512);
    gl_lds16(gah0 + 1024 + k0, lal0); gl_lds16(gah1 + 1024 + k0, lal0 + 512);
    gl_lds16(gbh0 + k0, lbh0);        gl_lds16(gbh1 + k0, lbh0 + 512);
    gl_lds16(gbl0 + k0, lbl0);        gl_lds16(gbl1 + k0, lbl0 + 512);
    __syncthreads();
    bf16x8 afh[4], afl[4], bfh[4], bfl[4];
#pragma unroll
    for (int i = 0; i < 4; ++i) {
      const int off = ((wr + (i << 4) + fcol) << 5) + koff;
      afh[i] = *(const bf16x8*)&Ahs[off];
      afl[i] = *(const bf16x8*)&Als[off];
    }
#pragma unroll
    for (int j = 0; j < 4; ++j) {
      const int off = ((wc + (j << 4) + fcol) << 5) + koff;
      bfh[j] = *(const bf16x8*)&Bhs[off];
      bfl[j] = *(const bf16x8*)&Bls[off];
    }
#pragma unroll
    for (int i = 0; i < 4; ++i)
#pragma unroll
      for (int j = 0; j < 4; ++j) {
        acc[i][j] = __builtin_amdgcn_mfma_f32_16x16x32_bf16(afh[i], bfh[j], acc[i][j], 0, 0, 0);
        acc[i][j] = __builtin_amdgcn_mfma_f32_16x16x32_bf16(afh[i], bfl[j], acc[i][j], 0, 0, 0);
        acc[i][j] = __builtin_amdgcn_mfma_f32_16x16x32_bf16(afl[i], bfh[j], acc[i][j], 0, 0, 0);
      }
  }

  const int qd = lane >> 4;
#pragma unroll
  for (int j = 0; j < 4; ++j) {
    const int n = n0 + wc + (j << 4) + fcol;
    const float bv = bias[n];
#pragma unroll
    for (int i = 0; i < 4; ++i)
#pragma unroll
      for (int r = 0; r < 4; ++r) {
        const int m = m0 + wr + (i << 4) + (qd << 2) + r;
        OUT[((size_t)m << 10) + n] = acc[i][j][r] + bv;
      }
  }
}

extern "C" void kernel_launch(void* const* d_in, const int* in_sizes, int n_in,
                              void* d_out, int out_size, void* d_ws, size_t ws_size,
                              hipStream_t stream) {
  const float* x      = (const float*)d_in[0];
  const float* W_attn = (const float*)d_in[1];
  const float* b_attn = (const float*)d_in[2];
  const float* W_proj = (const float*)d_in[3];
  const float* b_proj = (const float*)d_in[4];
  const float* sr     = (const float*)d_in[5];
  const float* gt     = (const float*)d_in[6];
  const float* noise  = (const float*)d_in[7];

  char* base = (char*)d_ws;
  // [0, 268435456): ATT fp32 (later overwritten in-place by P2 bf16).
  //   Prep aliases inside (dead after k_qkv3): A2q, Bhq, Blq.
  float*          ATT = (float*)base;
  unsigned short* A2q = (unsigned short*)base;                    // 16 MB
  unsigned short* Bhq = (unsigned short*)(base + 16777216);       //  6 MB
  unsigned short* Blq = (unsigned short*)(base + 23068672);       //  6 MB
  unsigned short* P2  = (unsigned short*)base;                    // in-place over ATT
  // [268435456, +16 MB): Q2; after k_att3 reused for W_proj split
  unsigned short* Q2  = (unsigned short*)(base + 268435456);
  unsigned short* Wph = (unsigned short*)(base + 268435456);
  unsigned short* Wpl = (unsigned short*)(base + 270532608);
  // [285212672, +16 MB): Kht+Klt; after k_att3 reused for Y2
  unsigned short* Kht = (unsigned short*)(base + 285212672);
  unsigned short* Klt = (unsigned short*)(base + 293601280);
  unsigned short* Y2  = (unsigned short*)(base + 285212672);
  // [301989888, +16 MB): Vht+Vlt
  unsigned short* Vht = (unsigned short*)(base + 301989888);
  unsigned short* Vlt = (unsigned short*)(base + 310378496);
  float* OUT = (float*)d_out;

  k_split_a2<<<dim3(4096),     256, 0, stream>>>(x, A2q);
  k_split_b2<<<dim3(96, 32),   256, 0, stream>>>(W_attn, Bhq, Blq, 3072, 1024);
  k_qkv3    <<<dim3(24, 32),   256, 0, stream>>>(A2q, Bhq, Blq, b_attn, Q2, Kht, Klt, Vht, Vlt);
  k_att3    <<<dim3(8, 8, 64), 256, 0, stream>>>(Q2, Kht, Klt, ATT);
  k_split_b2<<<dim3(32, 32),   256, 0, stream>>>(W_proj, Wph, Wpl, 1024, 1024);
  k_select  <<<dim3(16384),    256, 0, stream>>>(ATT, P2, noise, sr, gt);
  k_pv3     <<<dim3(8, 1, 64), 256, 0, stream>>>(P2, Vht, Vlt, Y2);
  k_proj3   <<<dim3(8, 32),    256, 0, stream>>>(Y2, Wph, Wpl, b_proj, OUT);
}